// Round 7
// baseline (422.708 us; speedup 1.0000x reference)
//
#include <hip/hip_runtime.h>

#define S_ 2048
#define D_ 1024
#define B_ 2
#define H_ 16
#define DK_ 64
#define HID_ 4096

typedef unsigned short u16;
typedef __attribute__((ext_vector_type(8))) short short8;
typedef __attribute__((ext_vector_type(4))) float f32x4;

// frag-linear slot with bank-spreading XOR: panel of 64 slots x 16B
#define SLOT(q16, r16) (((q16) * 16) + ((r16) ^ (q16)))

__device__ __forceinline__ float bf2f(u16 u) {
  return __uint_as_float(((unsigned int)u) << 16);
}
__device__ __forceinline__ u16 f2bf(float f) {
  unsigned int x = __float_as_uint(f);
  x += 0x7fff + ((x >> 16) & 1);
  return (u16)(x >> 16);
}
__device__ __forceinline__ unsigned int pk2bf(float lo, float hi) {
  return ((__float_as_uint(lo) + 0x8000u) >> 16) | ((__float_as_uint(hi) + 0x8000u) & 0xffff0000u);
}
// exact-RNE pack of two floats -> one u32 (two bf16)
__device__ __forceinline__ unsigned int pk2bf_rne(float lo, float hi) {
  return (unsigned int)f2bf(lo) | ((unsigned int)f2bf(hi) << 16);
}

// ---------------- prep: 6 weight transposes (f32 -> bf16, [K,N] -> [N,K]) ----
__global__ void prep_k(
    const float* __restrict__ Wq, const float* __restrict__ Wk,
    const float* __restrict__ Wv, const float* __restrict__ Wo,
    const float* __restrict__ W1, const float* __restrict__ W2,
    u16* __restrict__ WqT, u16* __restrict__ WkT, u16* __restrict__ WvT,
    u16* __restrict__ WoT, u16* __restrict__ W1T, u16* __restrict__ W2T) {
  const int z = blockIdx.z;
  __shared__ u16 tile[32][33];
  const float* in; u16* outp; int R, C;
  switch (z) {
    case 0: in = Wq; outp = WqT; R = 1024; C = 1024; break;
    case 1: in = Wk; outp = WkT; R = 1024; C = 1024; break;
    case 2: in = Wv; outp = WvT; R = 1024; C = 1024; break;
    case 3: in = Wo; outp = WoT; R = 1024; C = 1024; break;
    case 4: in = W1; outp = W1T; R = 1024; C = 4096; break;
    default: in = W2; outp = W2T; R = 4096; C = 1024; break;
  }
  int c0, r0;
  if (z == 5) { c0 = blockIdx.y * 32; r0 = blockIdx.x * 32; }
  else        { c0 = blockIdx.x * 32; r0 = blockIdx.y * 32; }
  if (c0 >= C || r0 >= R) return;
  const int tx = threadIdx.x, ty = threadIdx.y;
  for (int i = ty; i < 32; i += 8)
    tile[i][tx] = f2bf(in[(long)(r0 + i) * C + c0 + tx]);
  __syncthreads();
  for (int i = ty; i < 32; i += 8)
    outp[(long)(c0 + i) * R + r0 + tx] = tile[tx][i];
}

__global__ __launch_bounds__(256) void cvt2_k(const float* __restrict__ x, const float* __restrict__ y,
                                              u16* __restrict__ xb, u16* __restrict__ yb) {
  const int z = blockIdx.y;
  const float* in = z ? y : x;
  u16* outp = z ? yb : xb;
  const int i = blockIdx.x * 256 + threadIdx.x;
  float4 v = ((const float4*)in)[i];
  ((uint2*)outp)[i] = make_uint2(pk2bf_rne(v.x, v.y), pk2bf_rne(v.z, v.w));
}

// ---------------- generic bf16 GEMM: C[M,N] = A[M,K] @ Bt[N,K]^T ----------------
// Swapped-operand MFMA: acc holds C^T layout (row on l15, 4 consecutive cols
// on regs) -> vectorized 8B epilogue stores.
template<int MT, int NT, int OUTF32>
__global__ __launch_bounds__(256) void gemm_bt(
    const u16* __restrict__ A, const u16* __restrict__ Bt,
    const float* __restrict__ bias, void* __restrict__ Cv,
    int K, int lda, int ldb, int ldc,
    long sA, long sB, long sC, int relu) {
  constexpr int BM = MT * 32;
  constexpr int BN = NT * 32;
  __shared__ __align__(16) u16 As[BM * 32];
  __shared__ __align__(16) u16 Bs[BN * 32];
  const int z = blockIdx.z;
  A  += (long)z * sA;
  Bt += (long)z * sB;
  const int tid  = threadIdx.x;
  const int lane = tid & 63, wave = tid >> 6;
  const int quad = lane >> 4, l15 = lane & 15;
  const int wm = wave >> 1, wn = wave & 1;
  const u16* Ab = A  + (long)(blockIdx.y * BM) * lda;
  const u16* Bb = Bt + (long)(blockIdx.x * BN) * ldb;

  f32x4 acc[MT][NT];
#pragma unroll
  for (int i = 0; i < MT; ++i)
#pragma unroll
    for (int j = 0; j < NT; ++j) acc[i][j] = (f32x4){0.f, 0.f, 0.f, 0.f};

  const int r0  = tid >> 2;
  const int kk0 = (tid & 3) * 8;

  for (int kt = 0; kt < K; kt += 32) {
#pragma unroll
    for (int p = 0; p < BM / 64; ++p) {
      __builtin_amdgcn_global_load_lds(
          (const __attribute__((address_space(1))) void*)(Ab + (long)(p * 64 + r0) * lda + kt + kk0),
          (__attribute__((address_space(3))) void*)(&As[p * 2048 + tid * 8]), 16, 0, 0);
    }
#pragma unroll
    for (int p = 0; p < BN / 64; ++p) {
      __builtin_amdgcn_global_load_lds(
          (const __attribute__((address_space(1))) void*)(Bb + (long)(p * 64 + r0) * ldb + kt + kk0),
          (__attribute__((address_space(3))) void*)(&Bs[p * 2048 + tid * 8]), 16, 0, 0);
    }
    __syncthreads();
    short8 af[MT], bfr[NT];
#pragma unroll
    for (int mt = 0; mt < MT; ++mt)
      af[mt] = *(const short8*)&As[(wm * (MT * 16) + mt * 16 + l15) * 32 + quad * 8];
#pragma unroll
    for (int nt = 0; nt < NT; ++nt)
      bfr[nt] = *(const short8*)&Bs[(wn * (NT * 16) + nt * 16 + l15) * 32 + quad * 8];
#pragma unroll
    for (int mt = 0; mt < MT; ++mt)
#pragma unroll
      for (int nt = 0; nt < NT; ++nt)
        acc[mt][nt] = __builtin_amdgcn_mfma_f32_16x16x32_bf16(bfr[nt], af[mt], acc[mt][nt], 0, 0, 0);
    __syncthreads();
  }

  // epilogue (C^T layout): row = mt*16 + l15, cols = nt*16 + quad*4 + r
#pragma unroll
  for (int mt = 0; mt < MT; ++mt) {
    const long row = blockIdx.y * BM + wm * (MT * 16) + mt * 16 + l15;
#pragma unroll
    for (int nt = 0; nt < NT; ++nt) {
      const int colb = blockIdx.x * BN + wn * (NT * 16) + nt * 16 + quad * 4;
      float4 b4 = bias ? *(const float4*)&bias[colb] : make_float4(0.f, 0.f, 0.f, 0.f);
      float v0 = acc[mt][nt][0] + b4.x;
      float v1 = acc[mt][nt][1] + b4.y;
      float v2 = acc[mt][nt][2] + b4.z;
      float v3 = acc[mt][nt][3] + b4.w;
      if (relu) {
        v0 = fmaxf(v0, 0.f); v1 = fmaxf(v1, 0.f);
        v2 = fmaxf(v2, 0.f); v3 = fmaxf(v3, 0.f);
      }
      if (OUTF32) {
        *(float4*)&((float*)Cv)[(long)z * sC + row * ldc + colb] = make_float4(v0, v1, v2, v3);
      } else {
        *(uint2*)&((u16*)Cv)[(long)z * sC + row * ldc + colb] =
            make_uint2(pk2bf_rne(v0, v1), pk2bf_rne(v2, v3));
      }
    }
  }
}

// ---------------- QKV batched GEMM (Q pre-scaled by 0.125*log2e) -------------
__global__ __launch_bounds__(256) void qkv_k(
    const u16* __restrict__ xb, const u16* __restrict__ yb,
    const u16* __restrict__ WqT, const u16* __restrict__ WkT, const u16* __restrict__ WvT,
    const float* __restrict__ bq, const float* __restrict__ bk, const float* __restrict__ bv,
    u16* __restrict__ Q, u16* __restrict__ Kp, u16* __restrict__ Vp) {
  __shared__ __align__(16) u16 As[128 * 32];
  __shared__ __align__(16) u16 Bs[128 * 32];
  const int z = blockIdx.z;
  const u16* A  = (z == 0) ? xb : yb;
  const u16* Bt = (z == 0) ? WqT : (z == 1) ? WkT : WvT;
  const float* bias = (z == 0) ? bq : (z == 1) ? bk : bv;
  u16* C = (z == 0) ? Q : (z == 1) ? Kp : Vp;
  const float sc = (z == 0) ? 0.18033688011112042f : 1.0f;  // 0.125*log2(e)
  const int tid  = threadIdx.x;
  const int lane = tid & 63, wave = tid >> 6;
  const int quad = lane >> 4, l15 = lane & 15;
  const int wm = wave >> 1, wn = wave & 1;
  const u16* Ab = A  + (long)(blockIdx.y * 128) * D_;
  const u16* Bb = Bt + (long)(blockIdx.x * 128) * D_;

  f32x4 acc[4][4];
#pragma unroll
  for (int i = 0; i < 4; ++i)
#pragma unroll
    for (int j = 0; j < 4; ++j) acc[i][j] = (f32x4){0.f, 0.f, 0.f, 0.f};

  const int r0  = tid >> 2;
  const int kk0 = (tid & 3) * 8;

  for (int kt = 0; kt < D_; kt += 32) {
#pragma unroll
    for (int p = 0; p < 2; ++p) {
      __builtin_amdgcn_global_load_lds(
          (const __attribute__((address_space(1))) void*)(Ab + (long)(p * 64 + r0) * D_ + kt + kk0),
          (__attribute__((address_space(3))) void*)(&As[p * 2048 + tid * 8]), 16, 0, 0);
      __builtin_amdgcn_global_load_lds(
          (const __attribute__((address_space(1))) void*)(Bb + (long)(p * 64 + r0) * D_ + kt + kk0),
          (__attribute__((address_space(3))) void*)(&Bs[p * 2048 + tid * 8]), 16, 0, 0);
    }
    __syncthreads();
    short8 af[4], bfr[4];
#pragma unroll
    for (int mt = 0; mt < 4; ++mt)
      af[mt] = *(const short8*)&As[(wm * 64 + mt * 16 + l15) * 32 + quad * 8];
#pragma unroll
    for (int nt = 0; nt < 4; ++nt)
      bfr[nt] = *(const short8*)&Bs[(wn * 64 + nt * 16 + l15) * 32 + quad * 8];
#pragma unroll
    for (int mt = 0; mt < 4; ++mt)
#pragma unroll
      for (int nt = 0; nt < 4; ++nt)
        acc[mt][nt] = __builtin_amdgcn_mfma_f32_16x16x32_bf16(bfr[nt], af[mt], acc[mt][nt], 0, 0, 0);
    __syncthreads();
  }

#pragma unroll
  for (int mt = 0; mt < 4; ++mt) {
    const long row = blockIdx.y * 128 + wm * 64 + mt * 16 + l15;
#pragma unroll
    for (int nt = 0; nt < 4; ++nt) {
      const int colb = blockIdx.x * 128 + wn * 64 + nt * 16 + quad * 4;
      const float4 b4 = *(const float4*)&bias[colb];
      float v0 = (acc[mt][nt][0] + b4.x) * sc;
      float v1 = (acc[mt][nt][1] + b4.y) * sc;
      float v2 = (acc[mt][nt][2] + b4.z) * sc;
      float v3 = (acc[mt][nt][3] + b4.w) * sc;
      *(uint2*)&C[row * D_ + colb] = make_uint2(pk2bf_rne(v0, v1), pk2bf_rne(v2, v3));
    }
  }
}

// ---------------- V[b,s,h*64+d] -> Vt[bh][d][s] ----------------
__global__ void vtrans_k(const u16* __restrict__ V, u16* __restrict__ Vt) {
  __shared__ u16 tile[32][33];
  const int bh = blockIdx.z, b = bh >> 4, h = bh & 15;
  const u16* in = V + (long)b * S_ * D_ + h * DK_;
  u16* outp = Vt + (long)bh * DK_ * S_;
  const int s0 = blockIdx.x * 32, d0 = blockIdx.y * 32;
  const int tx = threadIdx.x, ty = threadIdx.y;
  for (int i = ty; i < 32; i += 8)
    tile[i][tx] = in[(long)(s0 + i) * D_ + d0 + tx];
  __syncthreads();
  for (int i = ty; i < 32; i += 8)
    outp[(long)(d0 + i) * S_ + s0 + tx] = tile[tx][i];
}

// ---------------- fused flash attention v5 ----------------
// v4 + swapped-operand PV accumulate: accO in C^T layout (q row on l15,
// 4 consecutive d on regs) -> 8B ctx stores + per-lane l-normalization.
__global__ __launch_bounds__(256, 4) void flash_k(
    const u16* __restrict__ Q, const u16* __restrict__ Kp, const u16* __restrict__ Vt,
    const int* __restrict__ mask, u16* __restrict__ ctx) {
  __shared__ __align__(16) u16 sQ[8192];       // 16KB: 8 panels
  __shared__ __align__(16) u16 sK[2][2048];    // 8KB
  __shared__ __align__(16) u16 sV[2][2048];    // 8KB
  __shared__ __align__(16) u16 sP[4][1024];    // 8KB: per-wave 2 panels

  const int bh = blockIdx.x, qt = blockIdx.y;
  const int b = bh >> 4, h = bh & 15;
  const int tid = threadIdx.x;
  const int w = tid >> 6, lane = tid & 63;
  const int quad = lane >> 4, l15 = lane & 15;

  const u16* Qg  = Q  + ((long)b * S_ + qt * 128) * D_ + h * DK_;
  const u16* Kg  = Kp + (long)b * S_ * D_ + h * DK_;
  const u16* Vtg = Vt + (long)bh * DK_ * S_;
  const int* maskg = mask + (long)b * S_;
  u16* ctxg = ctx + ((long)b * S_ + qt * 128) * D_ + h * DK_;

  const int krow = tid >> 3, kc = tid & 7;
  const u16* kptr = Kg + (long)krow * D_ + kc * 8;
  const int ksw = (((krow >> 4) * 2 + (kc >> 2)) * 64 + SLOT(kc & 3, krow & 15)) * 8;
  const int vrow = tid >> 2, vc = tid & 3;
  const u16* vptr = Vtg + (long)vrow * S_ + vc * 8;
  const int vsw = ((vrow >> 4) * 64 + SLOT(vc, vrow & 15)) * 8;

  uint4 kreg = *(const uint4*)kptr;
  uint4 vreg = *(const uint4*)vptr;

#pragma unroll
  for (int p = 0; p < 4; ++p) {
    const int idx = p * 256 + tid;
    const int row = idx >> 3, cb = idx & 7;
    uint4 v = *(const uint4*)(Qg + (long)row * D_ + cb * 8);
    *(uint4*)&sQ[(((row >> 4) * 2 + (cb >> 2)) * 64 + SLOT(cb & 3, row & 15)) * 8] = v;
  }
  *(uint4*)&sK[0][ksw] = kreg;
  *(uint4*)&sV[0][vsw] = vreg;
  kreg = *(const uint4*)(kptr + 32 * D_);
  vreg = *(const uint4*)(vptr + 32);
  kptr += 64 * D_;
  vptr += 64;
  __syncthreads();

  const int rslot = SLOT(quad, l15) * 8;

  short8 qf[2][2];
#pragma unroll
  for (int mf = 0; mf < 2; ++mf)
#pragma unroll
    for (int kt = 0; kt < 2; ++kt)
      qf[mf][kt] = *(const short8*)&sQ[(((w * 2 + mf) * 2 + kt) * 64) * 8 + rslot];

  float lsum[2] = {0.f, 0.f};
  f32x4 accO[2][4];
#pragma unroll
  for (int i = 0; i < 2; ++i)
#pragma unroll
    for (int j = 0; j < 4; ++j) accO[i][j] = (f32x4){0.f, 0.f, 0.f, 0.f};

  for (int t = 0; t < 64; ++t) {
    if (t) __syncthreads();
    const int buf = t & 1, nb = buf ^ 1;
    if (t < 63) {
      *(uint4*)&sK[nb][ksw] = kreg;
      *(uint4*)&sV[nb][vsw] = vreg;
      if (t < 62) {
        kreg = *(const uint4*)kptr;
        vreg = *(const uint4*)vptr;
        kptr += 32 * D_;
        vptr += 32;
      }
    }
    f32x4 accS[2][2];   // [mk][mf]
#pragma unroll
    for (int i = 0; i < 2; ++i)
#pragma unroll
      for (int j = 0; j < 2; ++j) accS[i][j] = (f32x4){0.f, 0.f, 0.f, 0.f};
#pragma unroll
    for (int kt = 0; kt < 2; ++kt) {
      short8 kf0 = *(const short8*)&sK[buf][(kt * 64) * 8 + rslot];
      short8 kf1 = *(const short8*)&sK[buf][((2 + kt) * 64) * 8 + rslot];
#pragma unroll
      for (int mf = 0; mf < 2; ++mf) {
        accS[0][mf] = __builtin_amdgcn_mfma_f32_16x16x32_bf16(kf0, qf[mf][kt], accS[0][mf], 0, 0, 0);
        accS[1][mf] = __builtin_amdgcn_mfma_f32_16x16x32_bf16(kf1, qf[mf][kt], accS[1][mf], 0, 0, 0);
      }
    }
    const int4 mv0 = *(const int4*)(maskg + t * 32 + quad * 4);
    const int4 mv1 = *(const int4*)(maskg + t * 32 + 16 + quad * 4);
#pragma unroll
    for (int mk = 0; mk < 2; ++mk) {
      const int4 mv = mk ? mv1 : mv0;
      const int qt2 = mk * 2 + (quad >> 1);
      const int j0 = (quad & 1) * 4;
#pragma unroll
      for (int mf = 0; mf < 2; ++mf) {
        float p0 = mv.x ? __builtin_amdgcn_exp2f(accS[mk][mf][0]) : 0.f;
        float p1 = mv.y ? __builtin_amdgcn_exp2f(accS[mk][mf][1]) : 0.f;
        float p2 = mv.z ? __builtin_amdgcn_exp2f(accS[mk][mf][2]) : 0.f;
        float p3 = mv.w ? __builtin_amdgcn_exp2f(accS[mk][mf][3]) : 0.f;
        lsum[mf] += (p0 + p1) + (p2 + p3);
        *(uint2*)&sP[w][(mf * 64 + SLOT(qt2, l15)) * 8 + j0] =
            make_uint2(pk2bf(p0, p1), pk2bf(p2, p3));
      }
    }
    // PV with swapped operands: accO = V^T-frag x P-frag -> q on l15, d on regs
    short8 pf0 = *(const short8*)&sP[w][0 + rslot];
    short8 pf1 = *(const short8*)&sP[w][64 * 8 + rslot];
#pragma unroll
    for (int n = 0; n < 4; ++n) {
      short8 vf = *(const short8*)&sV[buf][(n * 64) * 8 + rslot];
      accO[0][n] = __builtin_amdgcn_mfma_f32_16x16x32_bf16(vf, pf0, accO[0][n], 0, 0, 0);
      accO[1][n] = __builtin_amdgcn_mfma_f32_16x16x32_bf16(vf, pf1, accO[1][n], 0, 0, 0);
    }
  }

  // epilogue: lsum is per-lane for q = l15 after quad reduction
#pragma unroll
  for (int mf = 0; mf < 2; ++mf) {
    lsum[mf] += __shfl_xor(lsum[mf], 16, 64);
    lsum[mf] += __shfl_xor(lsum[mf], 32, 64);
    const float inv = 1.f / lsum[mf];
    const long row = w * 32 + mf * 16 + l15;
#pragma unroll
    for (int n = 0; n < 4; ++n) {
      float v0 = accO[mf][n][0] * inv;
      float v1 = accO[mf][n][1] * inv;
      float v2 = accO[mf][n][2] * inv;
      float v3 = accO[mf][n][3] * inv;
      *(uint2*)&ctxg[row * D_ + n * 16 + quad * 4] =
          make_uint2(pk2bf_rne(v0, v1), pk2bf_rne(v2, v3));
    }
  }
}

// ---------------- add + layernorm helpers ----------------
__device__ __forceinline__ float block_reduce_sum(float v, float* red) {
#pragma unroll
  for (int off = 32; off; off >>= 1) v += __shfl_down(v, off, 64);
  __syncthreads();
  if ((threadIdx.x & 63) == 0) red[threadIdx.x >> 6] = v;
  __syncthreads();
  return red[0] + red[1] + red[2] + red[3];
}

// x (fp32) + mha0 + mha1 (bf16 split-K partials) + bo -> LN -> x1 (bf16)
__global__ __launch_bounds__(256) void addln_fb(const float* __restrict__ A,
    const u16* __restrict__ M0, const u16* __restrict__ M1, const float* __restrict__ bo,
    const float* __restrict__ g, const float* __restrict__ be, u16* __restrict__ outp) {
  __shared__ float red[4];
  const int row = blockIdx.x, tid = threadIdx.x;
  const float4 av = ((const float4*)(A + (long)row * D_))[tid];
  const uint2 m0 = ((const uint2*)(M0 + (long)row * D_))[tid];
  const uint2 m1 = ((const uint2*)(M1 + (long)row * D_))[tid];
  const int c0 = tid * 4;
  float xv[4];
  xv[0] = av.x + bf2f((u16)(m0.x & 0xffff)) + bf2f((u16)(m1.x & 0xffff)) + bo[c0 + 0];
  xv[1] = av.y + bf2f((u16)(m0.x >> 16))    + bf2f((u16)(m1.x >> 16))    + bo[c0 + 1];
  xv[2] = av.z + bf2f((u16)(m0.y & 0xffff)) + bf2f((u16)(m1.y & 0xffff)) + bo[c0 + 2];
  xv[3] = av.w + bf2f((u16)(m0.y >> 16))    + bf2f((u16)(m1.y >> 16))    + bo[c0 + 3];
  float s  = xv[0] + xv[1] + xv[2] + xv[3];
  float ss = xv[0]*xv[0] + xv[1]*xv[1] + xv[2]*xv[2] + xv[3]*xv[3];
  s  = block_reduce_sum(s, red);
  ss = block_reduce_sum(ss, red);
  const float m   = s * (1.0f / 1024.0f);
  const float var = ss * (1.0f / 1024.0f) - m * m;
  const float rs  = rsqrtf(var + 1e-5f);
  float v0 = (xv[0] - m) * rs * g[c0 + 0] + be[c0 + 0];
  float v1 = (xv[1] - m) * rs * g[c0 + 1] + be[c0 + 1];
  float v2 = (xv[2] - m) * rs * g[c0 + 2] + be[c0 + 2];
  float v3 = (xv[3] - m) * rs * g[c0 + 3] + be[c0 + 3];
  ((uint2*)(outp + (long)row * D_))[tid] = make_uint2(pk2bf_rne(v0, v1), pk2bf_rne(v2, v3));
}

// x1 (bf16) + ff0 + ff1 (bf16 split-K partials) + b2 -> LN -> out (fp32)
__global__ __launch_bounds__(256) void addln2_bf(const u16* __restrict__ A,
    const u16* __restrict__ F0, const u16* __restrict__ F1, const float* __restrict__ b2,
    const float* __restrict__ g, const float* __restrict__ be, float* __restrict__ outp) {
  __shared__ float red[4];
  const int row = blockIdx.x, tid = threadIdx.x;
  const uint2 av = ((const uint2*)(A + (long)row * D_))[tid];
  const uint2 f0 = ((const uint2*)(F0 + (long)row * D_))[tid];
  const uint2 f1 = ((const uint2*)(F1 + (long)row * D_))[tid];
  const int c0 = tid * 4;
  float xv[4];
  xv[0] = bf2f((u16)(av.x & 0xffff)) + bf2f((u16)(f0.x & 0xffff)) + bf2f((u16)(f1.x & 0xffff)) + b2[c0 + 0];
  xv[1] = bf2f((u16)(av.x >> 16))    + bf2f((u16)(f0.x >> 16))    + bf2f((u16)(f1.x >> 16))    + b2[c0 + 1];
  xv[2] = bf2f((u16)(av.y & 0xffff)) + bf2f((u16)(f0.y & 0xffff)) + bf2f((u16)(f1.y & 0xffff)) + b2[c0 + 2];
  xv[3] = bf2f((u16)(av.y >> 16))    + bf2f((u16)(f0.y >> 16))    + bf2f((u16)(f1.y >> 16))    + b2[c0 + 3];
  float s  = xv[0] + xv[1] + xv[2] + xv[3];
  float ss = xv[0]*xv[0] + xv[1]*xv[1] + xv[2]*xv[2] + xv[3]*xv[3];
  s  = block_reduce_sum(s, red);
  ss = block_reduce_sum(ss, red);
  const float m   = s * (1.0f / 1024.0f);
  const float var = ss * (1.0f / 1024.0f) - m * m;
  const float rs  = rsqrtf(var + 1e-5f);
  float4 o;
  o.x = (xv[0] - m) * rs * g[c0 + 0] + be[c0 + 0];
  o.y = (xv[1] - m) * rs * g[c0 + 1] + be[c0 + 1];
  o.z = (xv[2] - m) * rs * g[c0 + 2] + be[c0 + 2];
  o.w = (xv[3] - m) * rs * g[c0 + 3] + be[c0 + 3];
  ((float4*)(outp + (long)row * D_))[tid] = o;
}

extern "C" void kernel_launch(void* const* d_in, const int* in_sizes, int n_in,
                              void* d_out, int out_size, void* d_ws, size_t ws_size,
                              hipStream_t stream) {
  const float* x   = (const float*)d_in[0];
  const float* y   = (const float*)d_in[1];
  const int* mask  = (const int*)d_in[2];
  const float* Wq = (const float*)d_in[3];  const float* bq = (const float*)d_in[4];
  const float* Wk = (const float*)d_in[5];  const float* bk = (const float*)d_in[6];
  const float* Wv = (const float*)d_in[7];  const float* bv = (const float*)d_in[8];
  const float* Wo = (const float*)d_in[9];  const float* bo = (const float*)d_in[10];
  const float* W1 = (const float*)d_in[11]; const float* b1 = (const float*)d_in[12];
  const float* W2 = (const float*)d_in[13]; const float* b2 = (const float*)d_in[14];
  const float* g1 = (const float*)d_in[15]; const float* be1 = (const float*)d_in[16];
  const float* g2 = (const float*)d_in[17]; const float* be2 = (const float*)d_in[18];
  float* out = (float*)d_out;

  char* w = (char*)d_ws;
  const size_t MB = 1024 * 1024;
  u16* WqT = (u16*)(w + 0 * MB);
  u16* WkT = (u16*)(w + 2 * MB);
  u16* WvT = (u16*)(w + 4 * MB);
  u16* WoT = (u16*)(w + 6 * MB);
  u16* W1T = (u16*)(w + 8 * MB);     // 8MB  [HID][D]
  u16* W2T = (u16*)(w + 16 * MB);    // 8MB  [D][HID]
  u16* xb  = (u16*)(w + 24 * MB);    // dead after qkv; x1 reuses
  u16* yb  = (u16*)(w + 32 * MB);    // dead after qkv
  u16* Q   = (u16*)(w + 40 * MB);    // dead after flash; ff partials reuse
  u16* Kp  = (u16*)(w + 48 * MB);    // dead after flash
  u16* Vp  = (u16*)(w + 56 * MB);    // dead after vtrans
  u16* Vt  = (u16*)(w + 64 * MB);    // dead after flash
  u16* ctx = (u16*)(w + 72 * MB);    // dead after Wo gemm
  u16* mha = (u16*)(w + 80 * MB);    // 2 x 8MB bf16 split-K partials
  u16* x1  = (u16*)(w + 24 * MB);    // reuses xb; live through addln2
  u16* h1  = (u16*)(w + 96 * MB);    // 32MB bf16 [4096][4096]
  u16* ff  = (u16*)(w + 40 * MB);    // 2 x 8MB bf16 split-K partials

  prep_k<<<dim3(128, 32, 6), dim3(32, 8), 0, stream>>>(Wq, Wk, Wv, Wo, W1, W2,
      WqT, WkT, WvT, WoT, W1T, W2T);
  cvt2_k<<<dim3(4096, 2), 256, 0, stream>>>(x, y, xb, yb);

  qkv_k<<<dim3(8, 32, 3), 256, 0, stream>>>(xb, yb, WqT, WkT, WvT, bq, bk, bv, Q, Kp, Vp);

  vtrans_k<<<dim3(64, 2, 32), dim3(32, 8), 0, stream>>>(Vp, Vt);

  flash_k<<<dim3(32, 16), 256, 0, stream>>>(Q, Kp, Vt, mask, ctx);

  gemm_bt<4, 4, 0><<<dim3(8, 32, 2), 256, 0, stream>>>(ctx, WoT, nullptr, mha,
      512, 1024, 1024, 1024, 512, 512, (long)4096 * 1024, 0);
  addln_fb<<<dim3(4096), 256, 0, stream>>>(x, mha, mha + (long)4096 * 1024, bo, g1, be1, x1);

  gemm_bt<4, 4, 0><<<dim3(32, 32, 1), 256, 0, stream>>>(x1, W1T, b1, h1,
      1024, 1024, 1024, 4096, 0, 0, 0, 1);
  gemm_bt<4, 4, 0><<<dim3(8, 32, 2), 256, 0, stream>>>(h1, W2T, nullptr, ff,
      2048, 4096, 4096, 1024, 2048, 2048, (long)4096 * 1024, 0);
  addln2_bf<<<dim3(4096), 256, 0, stream>>>(x1, ff, ff + (long)4096 * 1024, b2, g2, be2, out);
}